// Round 2
// baseline (59.958 us; speedup 1.0000x reference)
//
#include <hip/hip_runtime.h>

// Closed form derived from the circuit (verified round 1, absmax 3.9e-3):
//   Product state per qubit; ZZZZ conjugated through CX(0,1),CX(2,3) -> Z1 (x) Z3;
//   RZ diagonal -> no effect on |amp|^2.
//   out[b] = cos(theta[1]) * cos(theta[3]) * cospi(x[b,1]) * cospi(x[b,3])
//
// Pure memory-bound elementwise: 8 MB read + 2 MB write. 4 rows/thread,
// per-instruction coalesced float4 loads + coalesced dword stores.

__global__ __launch_bounds__(256) void qlayer_expect(
    const float4* __restrict__ x,      // [B] rows of 4 floats
    const float* __restrict__ theta,   // [8]
    float* __restrict__ out,           // [B]
    int B)
{
    // Each block handles 4*256 = 1024 consecutive rows in 4 coalesced sweeps.
    int base = blockIdx.x * 1024 + threadIdx.x;
    float scale = cosf(theta[1]) * cosf(theta[3]);   // uniform, scalar-path
#pragma unroll
    for (int k = 0; k < 4; ++k) {
        int i = base + k * 256;
        if (i < B) {
            float4 r = x[i];                          // global_load_dwordx4, coalesced
            out[i] = scale * cospif(r.y) * cospif(r.w); // coalesced dword store
        }
    }
}

extern "C" void kernel_launch(void* const* d_in, const int* in_sizes, int n_in,
                              void* d_out, int out_size, void* d_ws, size_t ws_size,
                              hipStream_t stream) {
    const float4* x     = (const float4*)d_in[0];   // [B,4] f32
    const float*  theta = (const float*)d_in[1];    // [8] f32
    float*        out   = (float*)d_out;            // [B,1] f32
    int B = in_sizes[0] / 4;
    int blocks = (B + 1023) / 1024;                 // 512 blocks @ B=524288
    qlayer_expect<<<blocks, 256, 0, stream>>>(x, theta, out, B);
}